// Round 3
// baseline (359.571 us; speedup 1.0000x reference)
//
#include <hip/hip_runtime.h>
#include <hip/hip_bf16.h>
#include <math.h>
#include <utility>

typedef __hip_bfloat16 bf16;
typedef __attribute__((ext_vector_type(8))) short bf16x8;   // 8 bf16 = 4 VGPRs (MFMA A/B frag)
typedef __attribute__((ext_vector_type(4))) float floatx4;  // MFMA C/D frag

// async global->LDS, 16B per lane. LDS dest = wave-uniform base + lane*16.
__device__ __forceinline__ void async_copy16(const bf16* g, bf16* l) {
    __builtin_amdgcn_global_load_lds(
        (__attribute__((address_space(1))) void*)(void*)g,
        (__attribute__((address_space(3))) void*)(void*)l,
        16, 0, 0);
}

// ---------------- cast x: fp32 -> bf16, float4-vectorized ----------------
__global__ __launch_bounds__(256) void cast_f32_bf16(const float* __restrict__ in,
                                                     bf16* __restrict__ out, int n4) {
    int i = blockIdx.x * 256 + threadIdx.x;
    if (i >= n4) return;
    float4 v = ((const float4*)in)[i];
    union { ushort4 u; bf16 b[4]; } o;
    o.b[0] = __float2bfloat16(v.x);
    o.b[1] = __float2bfloat16(v.y);
    o.b[2] = __float2bfloat16(v.z);
    o.b[3] = __float2bfloat16(v.w);
    ((ushort4*)out)[i] = o.u;
}

// ------- cast + transpose: in fp32 [K][N] -> out bf16 [N][K] (LDS tile) -------
__global__ __launch_bounds__(256) void cast_transpose(const float* __restrict__ in,
                                                      bf16* __restrict__ out, int K, int N) {
    __shared__ float tile[32][33];
    int nb = blockIdx.x * 32, kb = blockIdx.y * 32;
    for (int j = threadIdx.y; j < 32; j += 8)
        tile[j][threadIdx.x] = in[(size_t)(kb + j) * N + nb + threadIdx.x];
    __syncthreads();
    for (int j = threadIdx.y; j < 32; j += 8)
        out[(size_t)(nb + j) * K + kb + threadIdx.x] = __float2bfloat16(tile[threadIdx.x][j]);
}

// ---------------- m97-style bf16 GEMM, XOR-swizzled LDS ----------------
// Chunk swizzle: 16B chunk x of row r stored at position x ^ ((r>>1)&3).
// Kills the 8-way bank conflict on b128 frag reads (stride-64B rows).
template <bool OUTF32>
__global__ __launch_bounds__(256) void gemm_bt(const bf16* __restrict__ A,
                                               const bf16* __restrict__ Bt,
                                               void* __restrict__ Cout,
                                               int M, int N, int K) {
    __shared__ bf16 As[128 * 32];
    __shared__ bf16 Bs[128 * 32];
    const int tid = threadIdx.x;
    const int wave = tid >> 6, lane = tid & 63;
    const int c = lane & 15, quad = lane >> 4;
    const int wm = wave >> 1, wn = wave & 1;
    const int mBase = blockIdx.y * 128, nBase = blockIdx.x * 128;

    const int sRow = lane >> 2;
    const int sCol = ((lane & 3) ^ ((lane >> 3) & 3)) << 3;   // swizzled source chunk
    const int rdOff = (quad ^ ((c >> 1) & 3)) << 3;           // swizzled read offset
    const bf16* gA = A + (size_t)(mBase + wave * 32 + sRow) * K + sCol;
    const bf16* gB = Bt + (size_t)(nBase + wave * 32 + sRow) * K + sCol;
    bf16* lA = As + wave * 1024;
    bf16* lB = Bs + wave * 1024;

    floatx4 acc[4][4];
#pragma unroll
    for (int mt = 0; mt < 4; mt++)
#pragma unroll
        for (int nt = 0; nt < 4; nt++) acc[mt][nt] = (floatx4){0.f, 0.f, 0.f, 0.f};

    for (int k0 = 0; k0 < K; k0 += 32) {
        async_copy16(gA + k0, lA);
        async_copy16(gA + k0 + 16 * K, lA + 512);
        async_copy16(gB + k0, lB);
        async_copy16(gB + k0 + 16 * K, lB + 512);
        __syncthreads();
        bf16x8 af[4], bfr[4];
#pragma unroll
        for (int mt = 0; mt < 4; mt++)
            af[mt] = *(const bf16x8*)(As + (wm * 64 + mt * 16 + c) * 32 + rdOff);
#pragma unroll
        for (int nt = 0; nt < 4; nt++)
            bfr[nt] = *(const bf16x8*)(Bs + (wn * 64 + nt * 16 + c) * 32 + rdOff);
#pragma unroll
        for (int mt = 0; mt < 4; mt++)
#pragma unroll
            for (int nt = 0; nt < 4; nt++)
                acc[mt][nt] = __builtin_amdgcn_mfma_f32_16x16x32_bf16(af[mt], bfr[nt],
                                                                      acc[mt][nt], 0, 0, 0);
        __syncthreads();
    }
#pragma unroll
    for (int mt = 0; mt < 4; mt++)
#pragma unroll
        for (int nt = 0; nt < 4; nt++)
#pragma unroll
            for (int r = 0; r < 4; r++) {
                int row = mBase + wm * 64 + mt * 16 + quad * 4 + r;
                int col = nBase + wn * 64 + nt * 16 + c;
                if (OUTF32)
                    ((float*)Cout)[(size_t)row * N + col] = acc[mt][nt][r];
                else
                    ((bf16*)Cout)[(size_t)row * N + col] = __float2bfloat16(acc[mt][nt][r]);
            }
}

// ---------------- RoPE (K only now), in place on bf16 ----------------
__global__ __launch_bounds__(256) void rope_kernel(bf16* __restrict__ X, int heads, int rowStride) {
    int idx = blockIdx.x * 256 + threadIdx.x;
    int d = idx & 63;
    int h = (idx >> 6) % heads;
    int row = idx / (heads * 64);
    int t = row & 2047;
    float theta = exp2f(-(float)d * 0.20762050593045827f);  // 10000^(-d/64)
    float ang = (float)t * theta;
    float sv, cv;
    __sincosf(ang, &sv, &cv);
    bf16* p = X + (size_t)row * rowStride + h * 128 + d;
    float x1 = __bfloat162float(p[0]);
    float x2 = __bfloat162float(p[64]);
    p[0]  = __float2bfloat16(x1 * cv - x2 * sv);
    p[64] = __float2bfloat16(x2 * cv + x1 * sv);
}

// ------- V transpose: QKV V-block [t][d] -> Vtg [b*4+kvh][d=128][t=2048] -------
__global__ __launch_bounds__(256) void vtrans(const bf16* __restrict__ QKV,
                                              bf16* __restrict__ Vtg) {
    __shared__ bf16 tile[32][34];
    const int bh = blockIdx.z;
    const int b = bh >> 2, kvh = bh & 3;
    const int t0 = blockIdx.x * 32, d0 = blockIdx.y * 32;
    const bf16* src = QKV + (size_t)b * 2048 * 3072 + 2560 + kvh * 128;
    for (int j = threadIdx.y; j < 32; j += 8)
        tile[j][threadIdx.x] = src[(size_t)(t0 + j) * 3072 + d0 + threadIdx.x];
    __syncthreads();
    bf16* dst = Vtg + (size_t)bh * 128 * 2048;
    for (int j = threadIdx.y; j < 32; j += 8)
        dst[(size_t)(d0 + j) * 2048 + t0 + threadIdx.x] = tile[threadIdx.x][j];
}

// ---------------- flash attention v3 (causal, GQA), bf16 MFMA ----------------
// One 64-row q-tile per block (1024 blocks, LPT order). Q-RoPE fused in-register.
// XOR-swizzled K/V staging (2-way max on frag reads). Diagonal tile split out.
// P round-trip interleaved per 32-key chunk (Pl = 5 KB; total LDS 37.9 KB ->
// 4 blocks/CU). No online max; row-sum reduced once at the end.
__global__ __launch_bounds__(256, 4) void flash_attn3(const bf16* __restrict__ QKV,
                                                      const bf16* __restrict__ Vtg,
                                                      bf16* __restrict__ AO) {
    const int T = 2048, STR = 3072;
    __shared__ bf16 Ks[4 * 64 * 32];      // 16 KB  [d-chunk][key 64][32]
    __shared__ bf16 Vs[2 * 128 * 32];     // 16 KB  [key-chunk][d 128][32]
    __shared__ bf16 Pl[4][16 * 40];       // 5 KB   per-wave P round-trip
    const int b = blockIdx.z, h = blockIdx.y;
    const int qtile = 31 - blockIdx.x;    // heaviest blocks dispatched first
    const int q0 = qtile * 64;
    const int kvh = h >> 2;
    const int tid = threadIdx.x, wave = tid >> 6, lane = tid & 63;
    const int c = lane & 15, quad = lane >> 4;
    const float C2 = 0.12751541717525597f;  // (1/sqrt(128)) * log2(e)

    const bf16* Kg = QKV + (size_t)b * T * STR + 2048 + kvh * 128;
    const bf16* Vg = Vtg + (size_t)(b * 4 + kvh) * 128 * 2048;
    const int srow = tid >> 2;                                  // 0..63
    const int xcol = ((tid & 3) ^ ((tid >> 3) & 3)) << 3;       // swizzled staging chunk
    const int koff = (quad ^ ((c >> 1) & 3)) << 3;              // swizzled read offset
    bf16* PlW = &Pl[wave][0];

    // ---- load Q frags and apply RoPE in-register ----
    bf16x8 qf[4];
    {
        const bf16* qp = QKV + ((size_t)b * T + q0 + wave * 16 + c) * STR + h * 128 + quad * 8;
#pragma unroll
        for (int ks = 0; ks < 4; ks++) qf[ks] = *(const bf16x8*)(qp + ks * 32);
        const float t = (float)(q0 + wave * 16 + c);
#pragma unroll
        for (int ks = 0; ks < 2; ks++)
#pragma unroll
            for (int j = 0; j < 8; j++) {
                int d = ks * 32 + quad * 8 + j;
                float theta = exp2f((float)d * -0.20762050593045827f);
                float sv, cv;
                __sincosf(t * theta, &sv, &cv);
                float lo = __bfloat162float(((const bf16*)&qf[ks])[j]);
                float hi = __bfloat162float(((const bf16*)&qf[ks + 2])[j]);
                ((bf16*)&qf[ks])[j]     = __float2bfloat16(lo * cv - hi * sv);
                ((bf16*)&qf[ks + 2])[j] = __float2bfloat16(hi * cv + lo * sv);
            }
    }

    floatx4 accO[8];
#pragma unroll
    for (int nt = 0; nt < 8; nt++) accO[nt] = (floatx4){0.f, 0.f, 0.f, 0.f};
    float lrow[4] = {0.f, 0.f, 0.f, 0.f};

    auto tile = [&](int kt0, auto DIAGC) {
        constexpr bool DIAG = decltype(DIAGC)::value;
#pragma unroll
        for (int it = 0; it < 4; it++) {
            async_copy16(Kg + (size_t)(kt0 + srow) * STR + it * 32 + xcol,
                         Ks + it * 2048 + wave * 512);
            async_copy16(Vg + (size_t)((it & 1) * 64 + srow) * 2048 + kt0 + (it >> 1) * 32 + xcol,
                         Vs + it * 2048 + wave * 512);
        }
        __syncthreads();
        // QK^T: S[16 q][64 key]
        floatx4 sf[4];
#pragma unroll
        for (int nt = 0; nt < 4; nt++) sf[nt] = (floatx4){0.f, 0.f, 0.f, 0.f};
#pragma unroll
        for (int ks = 0; ks < 4; ks++)
#pragma unroll
            for (int nt = 0; nt < 4; nt++) {
                bf16x8 kf = *(const bf16x8*)(Ks + ks * 2048 + (nt * 16 + c) * 32 + koff);
                sf[nt] = __builtin_amdgcn_mfma_f32_16x16x32_bf16(qf[ks], kf, sf[nt], 0, 0, 0);
            }
        // exp + P->LDS + PV, interleaved per 32-key chunk
#pragma unroll
        for (int kc = 0; kc < 2; kc++) {
#pragma unroll
            for (int nt2 = 0; nt2 < 2; nt2++) {
                const int nt = kc * 2 + nt2;
#pragma unroll
                for (int r = 0; r < 4; r++) {
                    float p = exp2f(sf[nt][r] * C2);
                    if (DIAG)
                        if (nt * 16 + c > wave * 16 + quad * 4 + r) p = 0.f;
                    lrow[r] += p;
                    PlW[(quad * 4 + r) * 40 + nt2 * 16 + c] = __float2bfloat16(p);
                }
            }
            asm volatile("s_waitcnt lgkmcnt(0)" ::: "memory");
            bf16x8 pf = *(const bf16x8*)(PlW + c * 40 + quad * 8);
#pragma unroll
            for (int nt = 0; nt < 8; nt++) {
                bf16x8 vf = *(const bf16x8*)(Vs + kc * 4096 + (nt * 16 + c) * 32 + koff);
                accO[nt] = __builtin_amdgcn_mfma_f32_16x16x32_bf16(pf, vf, accO[nt], 0, 0, 0);
            }
            asm volatile("" ::: "memory");
        }
        __syncthreads();
    };

    for (int kt0 = 0; kt0 < q0; kt0 += 64)
        tile(kt0, std::integral_constant<bool, false>{});
    tile(q0, std::integral_constant<bool, true>{});

    // finalize: reduce row-sum across the 16 column-lanes
    float inv[4];
#pragma unroll
    for (int r = 0; r < 4; r++) {
        float s = lrow[r];
        s += __shfl_xor(s, 1);
        s += __shfl_xor(s, 2);
        s += __shfl_xor(s, 4);
        s += __shfl_xor(s, 8);
        inv[r] = 1.0f / s;
    }
    const size_t orow = (size_t)b * T + q0 + wave * 16 + quad * 4;
#pragma unroll
    for (int nt = 0; nt < 8; nt++)
#pragma unroll
        for (int r = 0; r < 4; r++)
            AO[(orow + r) * 2048 + h * 128 + nt * 16 + c] =
                __float2bfloat16(accO[nt][r] * inv[r]);
}

extern "C" void kernel_launch(void* const* d_in, const int* in_sizes, int n_in,
                              void* d_out, int out_size, void* d_ws, size_t ws_size,
                              hipStream_t stream) {
    const float* x  = (const float*)d_in[0];
    const float* Wq = (const float*)d_in[1];
    const float* Wk = (const float*)d_in[2];
    const float* Wv = (const float*)d_in[3];
    const float* Wo = (const float*)d_in[4];

    char* ws = (char*)d_ws;
    bf16* xb  = (bf16*)(ws);                  // [4096][2048] (dead after QKV GEMM)
    bf16* Vtg = (bf16*)(ws);                  // reuses xb: [8][128][2048] = 4 MB
    bf16* Wt  = (bf16*)(ws + 16777216);       // [3072][2048] Wq|Wk|Wv
    bf16* Wot = (bf16*)(ws + 29360128);       // [2048][2048]
    bf16* QKV = (bf16*)(ws + 37748736);       // [4096][3072]
    bf16* AO  = (bf16*)(ws + 62914560);       // [4096][2048]

    cast_f32_bf16<<<8192, 256, 0, stream>>>(x, xb, 2097152);
    cast_transpose<<<dim3(64, 64), dim3(32, 8), 0, stream>>>(Wq, Wt, 2048, 2048);
    cast_transpose<<<dim3(16, 64), dim3(32, 8), 0, stream>>>(Wk, Wt + 2048 * 2048, 2048, 512);
    cast_transpose<<<dim3(16, 64), dim3(32, 8), 0, stream>>>(Wv, Wt + 2560 * 2048, 2048, 512);
    cast_transpose<<<dim3(64, 64), dim3(32, 8), 0, stream>>>(Wo, Wot, 2048, 2048);

    // QKV projection
    gemm_bt<false><<<dim3(24, 32), 256, 0, stream>>>(xb, Wt, QKV, 4096, 3072, 2048);

    // RoPE on K only (Q-RoPE fused into flash_attn3)
    rope_kernel<<<4096, 256, 0, stream>>>(QKV + 2048, 4, 3072);

    // V transpose (xb dead now)
    vtrans<<<dim3(64, 4, 8), dim3(32, 8), 0, stream>>>(QKV, Vtg);

    // flash attention: 32 q-tiles x 16 heads x 2 batch, LPT order
    flash_attn3<<<dim3(32, 16, 2), 256, 0, stream>>>(QKV, Vtg, AO);

    // output projection -> fp32 d_out
    gemm_bt<true><<<dim3(16, 32), 256, 0, stream>>>(AO, Wot, d_out, 4096, 2048, 2048);
}

// Round 4
// 345.692 us; speedup vs baseline: 1.0401x; 1.0401x over previous
//
#include <hip/hip_runtime.h>
#include <hip/hip_bf16.h>
#include <math.h>

typedef __hip_bfloat16 bf16;
typedef __attribute__((ext_vector_type(8))) short bf16x8;   // 8 bf16 = 4 VGPRs (MFMA A/B frag)
typedef __attribute__((ext_vector_type(4))) float floatx4;  // MFMA C/D frag

// async global->LDS, 16B per lane. LDS dest = wave-uniform base + lane*16.
__device__ __forceinline__ void async_copy16(const bf16* g, bf16* l) {
    __builtin_amdgcn_global_load_lds(
        (__attribute__((address_space(1))) void*)(void*)g,
        (__attribute__((address_space(3))) void*)(void*)l,
        16, 0, 0);
}

// ---------------- cast x: fp32 -> bf16, float4-vectorized ----------------
__global__ __launch_bounds__(256) void cast_f32_bf16(const float* __restrict__ in,
                                                     bf16* __restrict__ out, int n4) {
    int i = blockIdx.x * 256 + threadIdx.x;
    if (i >= n4) return;
    float4 v = ((const float4*)in)[i];
    union { ushort4 u; bf16 b[4]; } o;
    o.b[0] = __float2bfloat16(v.x);
    o.b[1] = __float2bfloat16(v.y);
    o.b[2] = __float2bfloat16(v.z);
    o.b[3] = __float2bfloat16(v.w);
    ((ushort4*)out)[i] = o.u;
}

// ------- cast + transpose: in fp32 [K][N] -> out bf16 [N][K] (LDS tile) -------
__global__ __launch_bounds__(256) void cast_transpose(const float* __restrict__ in,
                                                      bf16* __restrict__ out, int K, int N) {
    __shared__ float tile[32][33];
    int nb = blockIdx.x * 32, kb = blockIdx.y * 32;
    for (int j = threadIdx.y; j < 32; j += 8)
        tile[j][threadIdx.x] = in[(size_t)(kb + j) * N + nb + threadIdx.x];
    __syncthreads();
    for (int j = threadIdx.y; j < 32; j += 8)
        out[(size_t)(nb + j) * K + kb + threadIdx.x] = __float2bfloat16(tile[threadIdx.x][j]);
}

// ---------------- m97-style bf16 GEMM, XOR-swizzled LDS ----------------
template <bool OUTF32>
__global__ __launch_bounds__(256) void gemm_bt(const bf16* __restrict__ A,
                                               const bf16* __restrict__ Bt,
                                               void* __restrict__ Cout,
                                               int M, int N, int K) {
    __shared__ bf16 As[128 * 32];
    __shared__ bf16 Bs[128 * 32];
    const int tid = threadIdx.x;
    const int wave = tid >> 6, lane = tid & 63;
    const int c = lane & 15, quad = lane >> 4;
    const int wm = wave >> 1, wn = wave & 1;
    const int mBase = blockIdx.y * 128, nBase = blockIdx.x * 128;

    const int sRow = lane >> 2;
    const int sCol = ((lane & 3) ^ ((lane >> 3) & 3)) << 3;   // swizzled source chunk
    const int rdOff = (quad ^ ((c >> 1) & 3)) << 3;           // swizzled read offset
    const bf16* gA = A + (size_t)(mBase + wave * 32 + sRow) * K + sCol;
    const bf16* gB = Bt + (size_t)(nBase + wave * 32 + sRow) * K + sCol;
    bf16* lA = As + wave * 1024;
    bf16* lB = Bs + wave * 1024;

    floatx4 acc[4][4];
#pragma unroll
    for (int mt = 0; mt < 4; mt++)
#pragma unroll
        for (int nt = 0; nt < 4; nt++) acc[mt][nt] = (floatx4){0.f, 0.f, 0.f, 0.f};

    for (int k0 = 0; k0 < K; k0 += 32) {
        async_copy16(gA + k0, lA);
        async_copy16(gA + k0 + 16 * K, lA + 512);
        async_copy16(gB + k0, lB);
        async_copy16(gB + k0 + 16 * K, lB + 512);
        __syncthreads();
        bf16x8 af[4], bfr[4];
#pragma unroll
        for (int mt = 0; mt < 4; mt++)
            af[mt] = *(const bf16x8*)(As + (wm * 64 + mt * 16 + c) * 32 + rdOff);
#pragma unroll
        for (int nt = 0; nt < 4; nt++)
            bfr[nt] = *(const bf16x8*)(Bs + (wn * 64 + nt * 16 + c) * 32 + rdOff);
#pragma unroll
        for (int mt = 0; mt < 4; mt++)
#pragma unroll
            for (int nt = 0; nt < 4; nt++)
                acc[mt][nt] = __builtin_amdgcn_mfma_f32_16x16x32_bf16(af[mt], bfr[nt],
                                                                      acc[mt][nt], 0, 0, 0);
        __syncthreads();
    }
#pragma unroll
    for (int mt = 0; mt < 4; mt++)
#pragma unroll
        for (int nt = 0; nt < 4; nt++)
#pragma unroll
            for (int r = 0; r < 4; r++) {
                int row = mBase + wm * 64 + mt * 16 + quad * 4 + r;
                int col = nBase + wn * 64 + nt * 16 + c;
                if (OUTF32)
                    ((float*)Cout)[(size_t)row * N + col] = acc[mt][nt][r];
                else
                    ((bf16*)Cout)[(size_t)row * N + col] = __float2bfloat16(acc[mt][nt][r]);
            }
}

// ---------------- RoPE (K only), in place on bf16 ----------------
__global__ __launch_bounds__(256) void rope_kernel(bf16* __restrict__ X, int heads, int rowStride) {
    int idx = blockIdx.x * 256 + threadIdx.x;
    int d = idx & 63;
    int h = (idx >> 6) % heads;
    int row = idx / (heads * 64);
    int t = row & 2047;
    float theta = exp2f(-(float)d * 0.20762050593045827f);  // 10000^(-d/64)
    float ang = (float)t * theta;
    float sv, cv;
    __sincosf(ang, &sv, &cv);
    bf16* p = X + (size_t)row * rowStride + h * 128 + d;
    float x1 = __bfloat162float(p[0]);
    float x2 = __bfloat162float(p[64]);
    p[0]  = __float2bfloat16(x1 * cv - x2 * sv);
    p[64] = __float2bfloat16(x2 * cv + x1 * sv);
}

// ------- V transpose: QKV V-block [t][d] -> Vtg [b*4+kvh][d=128][t=2048] -------
__global__ __launch_bounds__(256) void vtrans(const bf16* __restrict__ QKV,
                                              bf16* __restrict__ Vtg) {
    __shared__ bf16 tile[32][34];
    const int bh = blockIdx.z;
    const int b = bh >> 2, kvh = bh & 3;
    const int t0 = blockIdx.x * 32, d0 = blockIdx.y * 32;
    const bf16* src = QKV + (size_t)b * 2048 * 3072 + 2560 + kvh * 128;
    for (int j = threadIdx.y; j < 32; j += 8)
        tile[j][threadIdx.x] = src[(size_t)(t0 + j) * 3072 + d0 + threadIdx.x];
    __syncthreads();
    bf16* dst = Vtg + (size_t)bh * 128 * 2048;
    for (int j = threadIdx.y; j < 32; j += 8)
        dst[(size_t)(d0 + j) * 2048 + t0 + threadIdx.x] = tile[threadIdx.x][j];
}

// ---------------- flash attention v4 (causal, GQA), bf16 MFMA ----------------
// Pair (pj, 31-pj): one kv-loop over the LONGER range; each staged tile serves
// both q-tiles -> uniform 33 tile-computes/block, ~17-32 stagings (halved),
// 256 MFMAs per staged tile. XOR-swizzled staging. Q-RoPE fused in-register.
// No online max; row-sum reduced once at the end.
__global__ __launch_bounds__(256, 2) void flash_attn4(const bf16* __restrict__ QKV,
                                                      const bf16* __restrict__ Vtg,
                                                      bf16* __restrict__ AO) {
    const int T = 2048, STR = 3072;
    __shared__ bf16 Ks[4 * 64 * 32];      // 16 KB  [d-chunk][key 64][32]
    __shared__ bf16 Vs[2 * 128 * 32];     // 16 KB  [key-chunk][d 128][32]
    __shared__ bf16 Pl[4][2][16 * 40];    // 10 KB  per-wave, per-chunk P round-trip
    const int b = blockIdx.z, h = blockIdx.y, pj = blockIdx.x;
    const int kvh = h >> 2;
    const int tid = threadIdx.x, wave = tid >> 6, lane = tid & 63;
    const int c = lane & 15, quad = lane >> 4;
    const float C2 = 0.12751541717525597f;  // (1/sqrt(128)) * log2(e)

    const int q0A = (31 - pj) * 64;       // longer phase (drives the kv loop)
    const int q0B = pj * 64;              // shorter phase

    const bf16* Kg = QKV + (size_t)b * T * STR + 2048 + kvh * 128;
    const bf16* Vg = Vtg + (size_t)(b * 4 + kvh) * 128 * 2048;
    const int srow = tid >> 2;
    const int xcol = ((tid & 3) ^ ((tid >> 3) & 3)) << 3;   // swizzled staging chunk
    const int koff = (quad ^ ((c >> 1) & 3)) << 3;          // swizzled read offset

    // ---- load Q frags for both phases, RoPE in-register ----
    bf16x8 qf[2][4];
    floatx4 accO[2][8];
    float lrow[2][4];
#pragma unroll
    for (int ph = 0; ph < 2; ph++) {
        const int q0 = ph ? q0B : q0A;
        const bf16* qp = QKV + ((size_t)b * T + q0 + wave * 16 + c) * STR + h * 128 + quad * 8;
#pragma unroll
        for (int ks = 0; ks < 4; ks++) qf[ph][ks] = *(const bf16x8*)(qp + ks * 32);
        const float t = (float)(q0 + wave * 16 + c);
#pragma unroll
        for (int ks = 0; ks < 2; ks++)
#pragma unroll
            for (int j = 0; j < 8; j++) {
                int d = ks * 32 + quad * 8 + j;
                float theta = exp2f((float)d * -0.20762050593045827f);
                float sv, cv;
                __sincosf(t * theta, &sv, &cv);
                float lo = __bfloat162float(((const bf16*)&qf[ph][ks])[j]);
                float hi = __bfloat162float(((const bf16*)&qf[ph][ks + 2])[j]);
                ((bf16*)&qf[ph][ks])[j]     = __float2bfloat16(lo * cv - hi * sv);
                ((bf16*)&qf[ph][ks + 2])[j] = __float2bfloat16(hi * cv + lo * sv);
            }
#pragma unroll
        for (int nt = 0; nt < 8; nt++) accO[ph][nt] = (floatx4){0.f, 0.f, 0.f, 0.f};
#pragma unroll
        for (int r = 0; r < 4; r++) lrow[ph][r] = 0.f;
    }

    // per-tile compute for one phase against the currently staged K/V tile
    auto compute = [&](int ph, bool diag) {
        floatx4 sf[4];
#pragma unroll
        for (int nt = 0; nt < 4; nt++) sf[nt] = (floatx4){0.f, 0.f, 0.f, 0.f};
#pragma unroll
        for (int ks = 0; ks < 4; ks++)
#pragma unroll
            for (int nt = 0; nt < 4; nt++) {
                bf16x8 kf = *(const bf16x8*)(Ks + ks * 2048 + (nt * 16 + c) * 32 + koff);
                sf[nt] = __builtin_amdgcn_mfma_f32_16x16x32_bf16(qf[ph][ks], kf, sf[nt], 0, 0, 0);
            }
        const int lim = diag ? (wave * 16 + quad * 4) : 1000;  // +r added below
#pragma unroll
        for (int kc = 0; kc < 2; kc++) {
            bf16* PlW = &Pl[wave][kc][0];
#pragma unroll
            for (int nt2 = 0; nt2 < 2; nt2++) {
                const int nt = kc * 2 + nt2;
#pragma unroll
                for (int r = 0; r < 4; r++) {
                    float p = exp2f(sf[nt][r] * C2);
                    if (nt * 16 + c > lim + r) p = 0.f;
                    lrow[ph][r] += p;
                    PlW[(quad * 4 + r) * 40 + nt2 * 16 + c] = __float2bfloat16(p);
                }
            }
            bf16x8 pf = *(const bf16x8*)(PlW + c * 40 + quad * 8);
#pragma unroll
            for (int nt = 0; nt < 8; nt++) {
                bf16x8 vf = *(const bf16x8*)(Vs + kc * 4096 + (nt * 16 + c) * 32 + koff);
                accO[ph][nt] = __builtin_amdgcn_mfma_f32_16x16x32_bf16(pf, vf, accO[ph][nt], 0, 0, 0);
            }
        }
    };

    for (int kt0 = 0; kt0 <= q0A; kt0 += 64) {
#pragma unroll
        for (int it = 0; it < 4; it++) {
            async_copy16(Kg + (size_t)(kt0 + srow) * STR + it * 32 + xcol,
                         Ks + it * 2048 + wave * 512);
            async_copy16(Vg + (size_t)((it & 1) * 64 + srow) * 2048 + kt0 + (it >> 1) * 32 + xcol,
                         Vs + it * 2048 + wave * 512);
        }
        __syncthreads();
        compute(0, kt0 == q0A);
        if (kt0 <= q0B) compute(1, kt0 == q0B);
        __syncthreads();
    }

    // finalize both phases
#pragma unroll
    for (int ph = 0; ph < 2; ph++) {
        const int q0 = ph ? q0B : q0A;
        float inv[4];
#pragma unroll
        for (int r = 0; r < 4; r++) {
            float s = lrow[ph][r];
            s += __shfl_xor(s, 1);
            s += __shfl_xor(s, 2);
            s += __shfl_xor(s, 4);
            s += __shfl_xor(s, 8);
            inv[r] = 1.0f / s;
        }
        const size_t orow = (size_t)b * T + q0 + wave * 16 + quad * 4;
#pragma unroll
        for (int nt = 0; nt < 8; nt++)
#pragma unroll
            for (int r = 0; r < 4; r++)
                AO[(orow + r) * 2048 + h * 128 + nt * 16 + c] =
                    __float2bfloat16(accO[ph][nt][r] * inv[r]);
    }
}

extern "C" void kernel_launch(void* const* d_in, const int* in_sizes, int n_in,
                              void* d_out, int out_size, void* d_ws, size_t ws_size,
                              hipStream_t stream) {
    const float* x  = (const float*)d_in[0];
    const float* Wq = (const float*)d_in[1];
    const float* Wk = (const float*)d_in[2];
    const float* Wv = (const float*)d_in[3];
    const float* Wo = (const float*)d_in[4];

    char* ws = (char*)d_ws;
    bf16* xb  = (bf16*)(ws);                  // [4096][2048] (dead after QKV GEMM)
    bf16* Vtg = (bf16*)(ws);                  // reuses xb: [8][128][2048] = 4 MB
    bf16* Wt  = (bf16*)(ws + 16777216);       // [3072][2048] Wq|Wk|Wv
    bf16* Wot = (bf16*)(ws + 29360128);       // [2048][2048]
    bf16* QKV = (bf16*)(ws + 37748736);       // [4096][3072]
    bf16* AO  = (bf16*)(ws + 62914560);       // [4096][2048]

    cast_f32_bf16<<<8192, 256, 0, stream>>>(x, xb, 2097152);
    cast_transpose<<<dim3(64, 64), dim3(32, 8), 0, stream>>>(Wq, Wt, 2048, 2048);
    cast_transpose<<<dim3(16, 64), dim3(32, 8), 0, stream>>>(Wk, Wt + 2048 * 2048, 2048, 512);
    cast_transpose<<<dim3(16, 64), dim3(32, 8), 0, stream>>>(Wv, Wt + 2560 * 2048, 2048, 512);
    cast_transpose<<<dim3(64, 64), dim3(32, 8), 0, stream>>>(Wo, Wot, 2048, 2048);

    // QKV projection
    gemm_bt<false><<<dim3(24, 32), 256, 0, stream>>>(xb, Wt, QKV, 4096, 3072, 2048);

    // RoPE on K only (Q-RoPE fused into flash_attn4)
    rope_kernel<<<4096, 256, 0, stream>>>(QKV + 2048, 4, 3072);

    // V transpose (xb dead now)
    vtrans<<<dim3(64, 4, 8), dim3(32, 8), 0, stream>>>(QKV, Vtg);

    // flash attention: 16 q-tile pairs x 16 heads x 2 batch (uniform 33 computes)
    flash_attn4<<<dim3(16, 16, 2), 256, 0, stream>>>(QKV, Vtg, AO);

    // output projection -> fp32 d_out
    gemm_bt<true><<<dim3(16, 32), 256, 0, stream>>>(AO, Wot, d_out, 4096, 2048, 2048);
}

// Round 5
// 326.148 us; speedup vs baseline: 1.1025x; 1.0599x over previous
//
#include <hip/hip_runtime.h>
#include <hip/hip_bf16.h>
#include <math.h>

typedef __hip_bfloat16 bf16;
typedef __attribute__((ext_vector_type(8))) short bf16x8;   // 8 bf16 = 4 VGPRs (MFMA A/B frag)
typedef __attribute__((ext_vector_type(4))) float floatx4;  // MFMA C/D frag

// async global->LDS, 16B per lane. LDS dest = wave-uniform base + lane*16.
__device__ __forceinline__ void async_copy16(const bf16* g, bf16* l) {
    __builtin_amdgcn_global_load_lds(
        (__attribute__((address_space(1))) void*)(void*)g,
        (__attribute__((address_space(3))) void*)(void*)l,
        16, 0, 0);
}

// ---------------- cast x: fp32 -> bf16, float4-vectorized ----------------
__global__ __launch_bounds__(256) void cast_f32_bf16(const float* __restrict__ in,
                                                     bf16* __restrict__ out, int n4) {
    int i = blockIdx.x * 256 + threadIdx.x;
    if (i >= n4) return;
    float4 v = ((const float4*)in)[i];
    union { ushort4 u; bf16 b[4]; } o;
    o.b[0] = __float2bfloat16(v.x);
    o.b[1] = __float2bfloat16(v.y);
    o.b[2] = __float2bfloat16(v.z);
    o.b[3] = __float2bfloat16(v.w);
    ((ushort4*)out)[i] = o.u;
}

// ------- cast + transpose: in fp32 [K][N] -> out bf16 [N][K] (LDS tile) -------
__global__ __launch_bounds__(256) void cast_transpose(const float* __restrict__ in,
                                                      bf16* __restrict__ out, int K, int N) {
    __shared__ float tile[32][33];
    int nb = blockIdx.x * 32, kb = blockIdx.y * 32;
    for (int j = threadIdx.y; j < 32; j += 8)
        tile[j][threadIdx.x] = in[(size_t)(kb + j) * N + nb + threadIdx.x];
    __syncthreads();
    for (int j = threadIdx.y; j < 32; j += 8)
        out[(size_t)(nb + j) * K + kb + threadIdx.x] = __float2bfloat16(tile[threadIdx.x][j]);
}

// ---------------- m97-style bf16 GEMM, XOR-swizzled LDS ----------------
template <bool OUTF32>
__global__ __launch_bounds__(256) void gemm_bt(const bf16* __restrict__ A,
                                               const bf16* __restrict__ Bt,
                                               void* __restrict__ Cout,
                                               int M, int N, int K) {
    __shared__ bf16 As[128 * 32];
    __shared__ bf16 Bs[128 * 32];
    const int tid = threadIdx.x;
    const int wave = tid >> 6, lane = tid & 63;
    const int c = lane & 15, quad = lane >> 4;
    const int wm = wave >> 1, wn = wave & 1;
    const int mBase = blockIdx.y * 128, nBase = blockIdx.x * 128;

    const int sRow = lane >> 2;
    const int sCol = ((lane & 3) ^ ((lane >> 3) & 3)) << 3;   // swizzled source chunk
    const int rdOff = (quad ^ ((c >> 1) & 3)) << 3;           // swizzled read offset
    const bf16* gA = A + (size_t)(mBase + wave * 32 + sRow) * K + sCol;
    const bf16* gB = Bt + (size_t)(nBase + wave * 32 + sRow) * K + sCol;
    bf16* lA = As + wave * 1024;
    bf16* lB = Bs + wave * 1024;

    floatx4 acc[4][4];
#pragma unroll
    for (int mt = 0; mt < 4; mt++)
#pragma unroll
        for (int nt = 0; nt < 4; nt++) acc[mt][nt] = (floatx4){0.f, 0.f, 0.f, 0.f};

    for (int k0 = 0; k0 < K; k0 += 32) {
        async_copy16(gA + k0, lA);
        async_copy16(gA + k0 + 16 * K, lA + 512);
        async_copy16(gB + k0, lB);
        async_copy16(gB + k0 + 16 * K, lB + 512);
        __syncthreads();
        bf16x8 af[4], bfr[4];
#pragma unroll
        for (int mt = 0; mt < 4; mt++)
            af[mt] = *(const bf16x8*)(As + (wm * 64 + mt * 16 + c) * 32 + rdOff);
#pragma unroll
        for (int nt = 0; nt < 4; nt++)
            bfr[nt] = *(const bf16x8*)(Bs + (wn * 64 + nt * 16 + c) * 32 + rdOff);
#pragma unroll
        for (int mt = 0; mt < 4; mt++)
#pragma unroll
            for (int nt = 0; nt < 4; nt++)
                acc[mt][nt] = __builtin_amdgcn_mfma_f32_16x16x32_bf16(af[mt], bfr[nt],
                                                                      acc[mt][nt], 0, 0, 0);
        __syncthreads();
    }
#pragma unroll
    for (int mt = 0; mt < 4; mt++)
#pragma unroll
        for (int nt = 0; nt < 4; nt++)
#pragma unroll
            for (int r = 0; r < 4; r++) {
                int row = mBase + wm * 64 + mt * 16 + quad * 4 + r;
                int col = nBase + wn * 64 + nt * 16 + c;
                if (OUTF32)
                    ((float*)Cout)[(size_t)row * N + col] = acc[mt][nt][r];
                else
                    ((bf16*)Cout)[(size_t)row * N + col] = __float2bfloat16(acc[mt][nt][r]);
            }
}

// ---------------- RoPE (K only), in place on bf16 ----------------
__global__ __launch_bounds__(256) void rope_kernel(bf16* __restrict__ X, int heads, int rowStride) {
    int idx = blockIdx.x * 256 + threadIdx.x;
    int d = idx & 63;
    int h = (idx >> 6) % heads;
    int row = idx / (heads * 64);
    int t = row & 2047;
    float theta = exp2f(-(float)d * 0.20762050593045827f);  // 10000^(-d/64)
    float ang = (float)t * theta;
    float sv, cv;
    __sincosf(ang, &sv, &cv);
    bf16* p = X + (size_t)row * rowStride + h * 128 + d;
    float x1 = __bfloat162float(p[0]);
    float x2 = __bfloat162float(p[64]);
    p[0]  = __float2bfloat16(x1 * cv - x2 * sv);
    p[64] = __float2bfloat16(x2 * cv + x1 * sv);
}

// ------- V transpose: QKV V-block [t][d] -> Vtg [b*4+kvh][d=128][t=2048] -------
__global__ __launch_bounds__(256) void vtrans(const bf16* __restrict__ QKV,
                                              bf16* __restrict__ Vtg) {
    __shared__ bf16 tile[32][34];
    const int bh = blockIdx.z;
    const int b = bh >> 2, kvh = bh & 3;
    const int t0 = blockIdx.x * 32, d0 = blockIdx.y * 32;
    const bf16* src = QKV + (size_t)b * 2048 * 3072 + 2560 + kvh * 128;
    for (int j = threadIdx.y; j < 32; j += 8)
        tile[j][threadIdx.x] = src[(size_t)(t0 + j) * 3072 + d0 + threadIdx.x];
    __syncthreads();
    bf16* dst = Vtg + (size_t)bh * 128 * 2048;
    for (int j = threadIdx.y; j < 32; j += 8)
        dst[(size_t)(d0 + j) * 2048 + t0 + threadIdx.x] = tile[threadIdx.x][j];
}

// ---------------- flash attention v5: split-kv partials (causal, GQA) ----------------
// No online max -> attention is linear in the kv range: partial (sum p*v, sum p)
// from disjoint ranges merge by addition. Pair (pj, 31-pj) has 33 kv tiles total;
// split across 2 blocks (17/16) -> 1024 perfectly uniform blocks, all resident
// at 4 blocks/CU (LDS 37 KB). Phases run sequentially -> single-phase register
// state (no spills). Scale*log2e folded into Q. XOR-swizzled staging.
// s=0: q-tile 31-pj, kv [0,17).  s=1: q-tile 31-pj kv [17,32-pj) -> Slot1,
// then q-tile pj kv [0,pj+1) -> Slot0.
__global__ __launch_bounds__(256, 4) void flash_attn5(const bf16* __restrict__ QKV,
                                                      const bf16* __restrict__ Vtg,
                                                      bf16* __restrict__ Slot0,
                                                      bf16* __restrict__ Slot1,
                                                      float* __restrict__ Ls) {
    const int T = 2048, STR = 3072;
    __shared__ bf16 Ks[4 * 64 * 32];      // 16 KB  [d-chunk][key 64][32]
    __shared__ bf16 Vs[2 * 128 * 32];     // 16 KB  [key-chunk][d 128][32]
    __shared__ bf16 Pl[4][16 * 40];       // 5 KB   per-wave P round-trip
    const int b = blockIdx.z, h = blockIdx.y;
    const int pj = blockIdx.x >> 1, s = blockIdx.x & 1;
    const int kvh = h >> 2;
    const int tid = threadIdx.x, wave = tid >> 6, lane = tid & 63;
    const int c = lane & 15, quad = lane >> 4;
    const float C2 = 0.12751541717525597f;  // (1/sqrt(128)) * log2(e), folded into Q

    const bf16* Kg = QKV + (size_t)b * T * STR + 2048 + kvh * 128;
    const bf16* Vg = Vtg + (size_t)(b * 4 + kvh) * 128 * 2048;
    const int srow = tid >> 2;
    const int xcol = ((tid & 3) ^ ((tid >> 3) & 3)) << 3;   // swizzled staging chunk
    const int koff = (quad ^ ((c >> 1) & 3)) << 3;          // swizzled read offset
    bf16* PlW = &Pl[wave][0];
    const int qa = 31 - pj;

    auto run_part = [&](int qtile, int ktlo, int kthi, bf16* slot, int lsSlot) {
        const int q0 = qtile * 64;
        // Q frags + RoPE + scale fold, in-register
        bf16x8 qf[4];
        {
            const bf16* qp = QKV + ((size_t)b * T + q0 + wave * 16 + c) * STR + h * 128 + quad * 8;
#pragma unroll
            for (int ks = 0; ks < 4; ks++) qf[ks] = *(const bf16x8*)(qp + ks * 32);
            const float t = (float)(q0 + wave * 16 + c);
#pragma unroll
            for (int ks = 0; ks < 2; ks++)
#pragma unroll
                for (int j = 0; j < 8; j++) {
                    int d = ks * 32 + quad * 8 + j;
                    float theta = exp2f((float)d * -0.20762050593045827f);
                    float sv, cv;
                    __sincosf(t * theta, &sv, &cv);
                    float lo = __bfloat162float(((const bf16*)&qf[ks])[j]);
                    float hi = __bfloat162float(((const bf16*)&qf[ks + 2])[j]);
                    ((bf16*)&qf[ks])[j]     = __float2bfloat16((lo * cv - hi * sv) * C2);
                    ((bf16*)&qf[ks + 2])[j] = __float2bfloat16((hi * cv + lo * sv) * C2);
                }
        }
        floatx4 accO[8];
#pragma unroll
        for (int nt = 0; nt < 8; nt++) accO[nt] = (floatx4){0.f, 0.f, 0.f, 0.f};
        float lrow[4] = {0.f, 0.f, 0.f, 0.f};

        for (int kt = ktlo; kt < kthi; kt++) {
            const int kt0 = kt * 64;
#pragma unroll
            for (int it = 0; it < 4; it++) {
                async_copy16(Kg + (size_t)(kt0 + srow) * STR + it * 32 + xcol,
                             Ks + it * 2048 + wave * 512);
                async_copy16(Vg + (size_t)((it & 1) * 64 + srow) * 2048 + kt0 + (it >> 1) * 32 + xcol,
                             Vs + it * 2048 + wave * 512);
            }
            __syncthreads();
            // QK^T: S[16 q][64 key]  (scale pre-folded)
            floatx4 sf[4];
#pragma unroll
            for (int nt = 0; nt < 4; nt++) sf[nt] = (floatx4){0.f, 0.f, 0.f, 0.f};
#pragma unroll
            for (int ks = 0; ks < 4; ks++)
#pragma unroll
                for (int nt = 0; nt < 4; nt++) {
                    bf16x8 kf = *(const bf16x8*)(Ks + ks * 2048 + (nt * 16 + c) * 32 + koff);
                    sf[nt] = __builtin_amdgcn_mfma_f32_16x16x32_bf16(qf[ks], kf, sf[nt], 0, 0, 0);
                }
            const int lim = (kt == qtile) ? (wave * 16 + quad * 4) : 1000;
#pragma unroll
            for (int kc = 0; kc < 2; kc++) {
#pragma unroll
                for (int nt2 = 0; nt2 < 2; nt2++) {
                    const int nt = kc * 2 + nt2;
#pragma unroll
                    for (int r = 0; r < 4; r++) {
                        float p = exp2f(sf[nt][r]);
                        if (nt * 16 + c > lim + r) p = 0.f;
                        lrow[r] += p;
                        PlW[(quad * 4 + r) * 40 + nt2 * 16 + c] = __float2bfloat16(p);
                    }
                }
                asm volatile("s_waitcnt lgkmcnt(0)" ::: "memory");
                bf16x8 pf = *(const bf16x8*)(PlW + c * 40 + quad * 8);
#pragma unroll
                for (int nt = 0; nt < 8; nt++) {
                    bf16x8 vf = *(const bf16x8*)(Vs + kc * 4096 + (nt * 16 + c) * 32 + koff);
                    accO[nt] = __builtin_amdgcn_mfma_f32_16x16x32_bf16(pf, vf, accO[nt], 0, 0, 0);
                }
                asm volatile("" ::: "memory");
            }
            __syncthreads();
        }
        // write partial row-sums (reduced over the 16 col-lanes) and partial O
        float sred[4];
#pragma unroll
        for (int r = 0; r < 4; r++) {
            float v = lrow[r];
            v += __shfl_xor(v, 1);
            v += __shfl_xor(v, 2);
            v += __shfl_xor(v, 4);
            v += __shfl_xor(v, 8);
            sred[r] = v;
        }
        if (c == 0) {
#pragma unroll
            for (int r = 0; r < 4; r++)
                Ls[(size_t)lsSlot * 65536 + ((size_t)(b * 16 + h) * 32 + qtile) * 64
                   + wave * 16 + quad * 4 + r] = sred[r];
        }
        const size_t orow = (size_t)b * T + q0 + wave * 16 + quad * 4;
#pragma unroll
        for (int nt = 0; nt < 8; nt++)
#pragma unroll
            for (int r = 0; r < 4; r++)
                slot[(orow + r) * 2048 + h * 128 + nt * 16 + c] =
                    __float2bfloat16(accO[nt][r]);
    };

    if (s == 0) {
        run_part(qa, 0, 17, Slot0, 0);
    } else {
        run_part(qa, 17, 32 - pj, Slot1, 1);   // empty for pj==15 -> writes zeros
        run_part(pj, 0, pj + 1, Slot0, 0);
    }
}

// ---------------- merge partials: AO = (Slot0 + Slot1) / (l0 + l1) ----------------
__global__ __launch_bounds__(256) void attn_merge(bf16* __restrict__ AO,
                                                  const bf16* __restrict__ P1,
                                                  const float* __restrict__ Ls) {
    int i = blockIdx.x * 256 + threadIdx.x;   // 1,048,576 threads, 8 cols each
    int row = i >> 8;                         // 0..4095
    int cg = (i & 255) << 3;                  // col 0..2040 step 8
    int b = row >> 11, t = row & 2047;
    int qtile = t >> 6;
    int h = cg >> 7;
    size_t off = (size_t)row * 2048 + cg;
    size_t li = ((size_t)(b * 16 + h) * 32 + qtile) * 64 + (t & 63);
    bf16x8 a0 = *(const bf16x8*)(AO + off);
    float l = Ls[li];
    float acc[8];
#pragma unroll
    for (int j = 0; j < 8; j++) acc[j] = __bfloat162float(((const bf16*)&a0)[j]);
    if (qtile >= 16) {   // q-tiles 16..31 have a second partial
        bf16x8 a1 = *(const bf16x8*)(P1 + off);
        l += Ls[65536 + li];
#pragma unroll
        for (int j = 0; j < 8; j++) acc[j] += __bfloat162float(((const bf16*)&a1)[j]);
    }
    float inv = 1.0f / l;
    bf16x8 o;
#pragma unroll
    for (int j = 0; j < 8; j++) ((bf16*)&o)[j] = __float2bfloat16(acc[j] * inv);
    *(bf16x8*)(AO + off) = o;
}

extern "C" void kernel_launch(void* const* d_in, const int* in_sizes, int n_in,
                              void* d_out, int out_size, void* d_ws, size_t ws_size,
                              hipStream_t stream) {
    const float* x  = (const float*)d_in[0];
    const float* Wq = (const float*)d_in[1];
    const float* Wk = (const float*)d_in[2];
    const float* Wv = (const float*)d_in[3];
    const float* Wo = (const float*)d_in[4];

    char* ws = (char*)d_ws;
    bf16* xb   = (bf16*)(ws);                 // [4096][2048] (dead after QKV GEMM)
    bf16* Vtg  = (bf16*)(ws);                 // reuses xb: [8][128][2048] = 4 MB
    bf16* Slt1 = (bf16*)(ws + 4194304);       // 16.78 MB, overlays dead xb-tail + Wt
    float* Ls  = (float*)(ws + 20971520);     // 0.5 MB lsum[2][b][h][qtile][64]
    bf16* Wt   = (bf16*)(ws + 16777216);      // [3072][2048] Wq|Wk|Wv (dead before flash)
    bf16* Wot  = (bf16*)(ws + 29360128);      // [2048][2048] (live until out-proj)
    bf16* QKV  = (bf16*)(ws + 37748736);      // [4096][3072]
    bf16* AO   = (bf16*)(ws + 62914560);      // [4096][2048] = partial Slot0, merged in place

    cast_f32_bf16<<<8192, 256, 0, stream>>>(x, xb, 2097152);
    cast_transpose<<<dim3(64, 64), dim3(32, 8), 0, stream>>>(Wq, Wt, 2048, 2048);
    cast_transpose<<<dim3(16, 64), dim3(32, 8), 0, stream>>>(Wk, Wt + 2048 * 2048, 2048, 512);
    cast_transpose<<<dim3(16, 64), dim3(32, 8), 0, stream>>>(Wv, Wt + 2560 * 2048, 2048, 512);
    cast_transpose<<<dim3(64, 64), dim3(32, 8), 0, stream>>>(Wo, Wot, 2048, 2048);

    // QKV projection (consumes xb, Wt — both dead afterwards)
    gemm_bt<false><<<dim3(24, 32), 256, 0, stream>>>(xb, Wt, QKV, 4096, 3072, 2048);

    // RoPE on K only (Q-RoPE fused into flash_attn5)
    rope_kernel<<<4096, 256, 0, stream>>>(QKV + 2048, 4, 3072);

    // V transpose (into Vtg at ws base)
    vtrans<<<dim3(64, 4, 8), dim3(32, 8), 0, stream>>>(QKV, Vtg);

    // split-kv flash attention: 16 pairs x 2 splits x 16 heads x 2 batch = 1024 uniform blocks
    flash_attn5<<<dim3(32, 16, 2), 256, 0, stream>>>(QKV, Vtg, AO, Slt1, Ls);

    // merge partials -> AO (in place)
    attn_merge<<<4096, 256, 0, stream>>>(AO, Slt1, Ls);

    // output projection -> fp32 d_out
    gemm_bt<true><<<dim3(16, 32), 256, 0, stream>>>(AO, Wot, d_out, 4096, 2048, 2048);
}